// Round 2
// baseline (713.920 us; speedup 1.0000x reference)
//
#include <hip/hip_runtime.h>
#include <hip/hip_fp16.h>

#define DEVFN __device__ __forceinline__

struct PlanePtrs { const float* p[9]; };

// Plane geometry (compile-time):
//   planes 0..5 temporal (tp0..tp5), 6..8 spatial (sp0..sp2)
//   W = 128 for all planes; H = 128 except planes 2,4,5 (H=100)
//   coord index per plane: A -> x-coord, B -> y-coord into c[4] = {posx,posy,posz,t}
__constant__ const int g_H[9] = {128,128,100,128,100,100,128,128,128};
__constant__ const int g_A[9] = {0,0,0,1,1,2,0,0,1};
__constant__ const int g_B[9] = {1,2,3,2,3,3,1,2,2};
// absolute texel prefix boundaries (monotone -> order-safe plane select)
__constant__ const int g_PRE[10] = {0,16384,32768,45568,61952,74752,87552,103936,120320,136704};
// transposed-plane base offsets in uint4 units (= g_PRE[pl] * 8)
__constant__ const int g_OFF4[9] = {0,131072,262144,364544,495616,598016,700416,831488,962560};

static const int TOTAL_TEXELS = 136704;           // g_PRE[9]
static const size_t WS_NEED   = 8749056ull * 2;   // halves * 2B = 17.5 MB

// ---------------------------------------------------------------------------
// Kernel 1: transpose planes [64,H,W] f32  ->  [H*W, 64] f16 in d_ws
// one thread per texel; dst texel index == gid (cumulative across planes)
// ---------------------------------------------------------------------------
__global__ __launch_bounds__(256) void k_transpose(PlanePtrs ptrs, __half* __restrict__ dst)
{
    int gid = blockIdx.x * 256 + threadIdx.x;

    // order-safe plane select: compare against absolute prefix boundaries
    int pl = 0;
    #pragma unroll
    for (int i = 1; i < 9; ++i) if (gid >= g_PRE[i]) pl = i;
    int tx   = gid - g_PRE[pl];
    int nTex = g_PRE[pl + 1] - g_PRE[pl];

    const float* src = ptrs.p[0];
    #pragma unroll
    for (int i = 1; i < 9; ++i) if (pl == i) src = ptrs.p[i];
    src += tx;

    uint4* __restrict__ out4 = reinterpret_cast<uint4*>(dst) + (size_t)gid * 8;
    #pragma unroll
    for (int j = 0; j < 8; ++j) {
        float f0 = src[(8*j+0)*nTex];
        float f1 = src[(8*j+1)*nTex];
        float f2 = src[(8*j+2)*nTex];
        float f3 = src[(8*j+3)*nTex];
        float f4 = src[(8*j+4)*nTex];
        float f5 = src[(8*j+5)*nTex];
        float f6 = src[(8*j+6)*nTex];
        float f7 = src[(8*j+7)*nTex];
        uint4 u;
        u.x = __builtin_bit_cast(unsigned int, __floats2half2_rn(f0, f1));
        u.y = __builtin_bit_cast(unsigned int, __floats2half2_rn(f2, f3));
        u.z = __builtin_bit_cast(unsigned int, __floats2half2_rn(f4, f5));
        u.w = __builtin_bit_cast(unsigned int, __floats2half2_rn(f6, f7));
        out4[j] = u;
    }
}

// ---------------------------------------------------------------------------
// Kernel 2: fused gather + MLP.
// block = 64 threads (1 wave), 64 points per block.
// Phase A: 8 groups x 8 lanes; group g gathers points 8g..8g+7, lane k owns
//          feature block k (feats 8k..8k+7). Per-plane bilinear combine in
//          packed fp16 (magnitude <= 0.5), cross-plane accumulate in fp32.
// Phase B: thread-per-point MLP; w0/w1/b0/b1 wave-uniform.
// ---------------------------------------------------------------------------
DEVFN void corner4f(unsigned a, unsigned b, unsigned c, unsigned d,
                    __half2 w00, __half2 w01, __half2 w10, __half2 w11,
                    float& ax, float& ay)
{
    __half2 t = __hmul2(__builtin_bit_cast(__half2, a), w00);
    t = __hfma2(__builtin_bit_cast(__half2, b), w01, t);
    t = __hfma2(__builtin_bit_cast(__half2, c), w10, t);
    t = __hfma2(__builtin_bit_cast(__half2, d), w11, t);
    ax += __low2float(t);
    ay += __high2float(t);
}

__global__ __launch_bounds__(64) void k_main(
    const float4* __restrict__ inp,
    const float*  __restrict__ aabb,
    const __half* __restrict__ planes,
    const float*  __restrict__ w0,
    const float*  __restrict__ b0,
    const float*  __restrict__ w1,
    const float*  __restrict__ b1,
    float*        __restrict__ out)
{
    __shared__ unsigned int lds[64 * 65];   // 64 pts x 64 feat-dwords, stride 65 (2-way on reads = free)

    const int tid  = threadIdx.x;
    const int g    = tid >> 3;
    const int k    = tid & 7;
    const int base = blockIdx.x * 64;

    float a0x = aabb[0], a0y = aabb[1], a0z = aabb[2];
    float sx  = aabb[3] - a0x, sy = aabb[4] - a0y, sz = aabb[5] - a0z;

    // ---------------- Phase A: gather ----------------
    for (int q = 0; q < 8; ++q) {
        const int p = g * 8 + q;
        float4 in = inp[base + p];
        float c[4];
        c[0] = (in.x - a0x) / sx * 2.0f - 1.0f;
        c[1] = (in.y - a0y) / sy * 2.0f - 1.0f;
        c[2] = (in.z - a0z) / sz * 2.0f - 1.0f;
        c[3] = in.w * 2.0f - 1.0f;

        float accT[8], accS[8];
        #pragma unroll
        for (int j = 0; j < 8; ++j) { accT[j] = 0.0f; accS[j] = 0.0f; }

        #pragma unroll
        for (int pl = 0; pl < 9; ++pl) {
            const int W = 128;
            const int H = g_H[pl];
            float fx = (c[g_A[pl]] + 1.0f) * 0.5f * (float)(W - 1);
            float fy = (c[g_B[pl]] + 1.0f) * 0.5f * (float)(H - 1);
            int x0 = min(max((int)floorf(fx), 0), W - 2);
            int y0 = min(max((int)floorf(fy), 0), H - 2);
            float wx = fx - (float)x0;
            float wy = fy - (float)y0;
            float iwx = 1.0f - wx, iwy = 1.0f - wy;

            const uint4* pb = reinterpret_cast<const uint4*>(planes)
                            + g_OFF4[pl] + ((y0 << 7) + x0) * 8 + k;
            uint4 v00 = pb[0];
            uint4 v01 = pb[8];
            uint4 v10 = pb[1024];
            uint4 v11 = pb[1032];

            __half2 w00h = __float2half2_rn(iwx * iwy);
            __half2 w01h = __float2half2_rn(wx  * iwy);
            __half2 w10h = __float2half2_rn(iwx * wy);
            __half2 w11h = __float2half2_rn(wx  * wy);

            if (pl < 6) {
                corner4f(v00.x, v01.x, v10.x, v11.x, w00h, w01h, w10h, w11h, accT[0], accT[1]);
                corner4f(v00.y, v01.y, v10.y, v11.y, w00h, w01h, w10h, w11h, accT[2], accT[3]);
                corner4f(v00.z, v01.z, v10.z, v11.z, w00h, w01h, w10h, w11h, accT[4], accT[5]);
                corner4f(v00.w, v01.w, v10.w, v11.w, w00h, w01h, w10h, w11h, accT[6], accT[7]);
            } else {
                corner4f(v00.x, v01.x, v10.x, v11.x, w00h, w01h, w10h, w11h, accS[0], accS[1]);
                corner4f(v00.y, v01.y, v10.y, v11.y, w00h, w01h, w10h, w11h, accS[2], accS[3]);
                corner4f(v00.z, v01.z, v10.z, v11.z, w00h, w01h, w10h, w11h, accS[4], accS[5]);
                corner4f(v00.w, v01.w, v10.w, v11.w, w00h, w01h, w10h, w11h, accS[6], accS[7]);
            }
        }

        #pragma unroll
        for (int j = 0; j < 4; ++j) {
            lds[p * 65 +      k * 4 + j] =
                __builtin_bit_cast(unsigned int, __floats2half2_rn(accT[2*j], accT[2*j+1]));
            lds[p * 65 + 32 + k * 4 + j] =
                __builtin_bit_cast(unsigned int, __floats2half2_rn(accS[2*j], accS[2*j+1]));
        }
    }

    __syncthreads();

    // ---------------- Phase B: MLP (thread-per-point) ----------------
    const int p = tid;
    const unsigned int* lrow = &lds[p * 65];
    float o0 = b1[0], o1 = b1[1], o2 = b1[2];

    #pragma unroll 1
    for (int jc = 0; jc < 64; jc += 16) {
        float h[16];
        #pragma unroll
        for (int jj = 0; jj < 16; ++jj) h[jj] = b0[jc + jj];

        #pragma unroll 4
        for (int d = 0; d < 64; ++d) {
            unsigned u = lrow[d];
            __half2 hv = __builtin_bit_cast(__half2, u);
            float f0 = __low2float(hv);
            float f1 = __high2float(hv);
            const float* wr = w0 + d * 128 + jc;   // w0 rows 2d and 2d+1 (row stride 64)
            #pragma unroll
            for (int jj = 0; jj < 16; ++jj) h[jj] = fmaf(f0, wr[jj], h[jj]);
            #pragma unroll
            for (int jj = 0; jj < 16; ++jj) h[jj] = fmaf(f1, wr[64 + jj], h[jj]);
        }

        #pragma unroll
        for (int jj = 0; jj < 16; ++jj) {
            float r = fmaxf(h[jj], 0.0f);
            const float* wq = w1 + (jc + jj) * 3;
            o0 = fmaf(r, wq[0], o0);
            o1 = fmaf(r, wq[1], o1);
            o2 = fmaf(r, wq[2], o2);
        }
    }

    long long oo = (long long)(base + p) * 3;
    out[oo + 0] = o0;
    out[oo + 1] = o1;
    out[oo + 2] = o2;
}

// ---------------------------------------------------------------------------
// Fallback (only if d_ws too small or N not divisible by 64): slow but correct,
// reads fp32 planes in original layout, accumulates h directly.
// ---------------------------------------------------------------------------
__global__ __launch_bounds__(256) void k_fallback(
    const float4* __restrict__ inp, const float* __restrict__ aabb, PlanePtrs ptrs,
    const float* __restrict__ w0, const float* __restrict__ b0,
    const float* __restrict__ w1, const float* __restrict__ b1,
    float* __restrict__ out, int N, int start)
{
    int pidx = start + blockIdx.x * 256 + threadIdx.x;
    if (pidx >= N) return;
    float4 in = inp[pidx];
    float c[4];
    c[0] = (in.x - aabb[0]) / (aabb[3] - aabb[0]) * 2.0f - 1.0f;
    c[1] = (in.y - aabb[1]) / (aabb[4] - aabb[1]) * 2.0f - 1.0f;
    c[2] = (in.z - aabb[2]) / (aabb[5] - aabb[2]) * 2.0f - 1.0f;
    c[3] = in.w * 2.0f - 1.0f;

    float h[64];
    #pragma unroll
    for (int j = 0; j < 64; ++j) h[j] = b0[j];

    #pragma unroll
    for (int pl = 0; pl < 9; ++pl) {
        const int W = 128, H = g_H[pl];
        float fx = (c[g_A[pl]] + 1.0f) * 0.5f * (float)(W - 1);
        float fy = (c[g_B[pl]] + 1.0f) * 0.5f * (float)(H - 1);
        int x0 = min(max((int)floorf(fx), 0), W - 2);
        int y0 = min(max((int)floorf(fy), 0), H - 2);
        float wx = fx - (float)x0, wy = fy - (float)y0;
        const float* P = ptrs.p[pl];
        int off = y0 * 128 + x0;
        int HW = H * 128;
        int row = (pl < 6) ? 0 : 64;
        for (int f = 0; f < 64; ++f) {
            const float* qp = P + f * HW + off;
            float v = (qp[0] * (1.0f - wx) + qp[1] * wx) * (1.0f - wy)
                    + (qp[128] * (1.0f - wx) + qp[129] * wx) * wy;
            const float* wr = w0 + (row + f) * 64;
            #pragma unroll
            for (int j = 0; j < 64; ++j) h[j] = fmaf(v, wr[j], h[j]);
        }
    }
    float o0 = b1[0], o1 = b1[1], o2 = b1[2];
    #pragma unroll
    for (int j = 0; j < 64; ++j) {
        float r = fmaxf(h[j], 0.0f);
        o0 = fmaf(r, w1[j * 3 + 0], o0);
        o1 = fmaf(r, w1[j * 3 + 1], o1);
        o2 = fmaf(r, w1[j * 3 + 2], o2);
    }
    out[(long long)pidx * 3 + 0] = o0;
    out[(long long)pidx * 3 + 1] = o1;
    out[(long long)pidx * 3 + 2] = o2;
}

// ---------------------------------------------------------------------------
extern "C" void kernel_launch(void* const* d_in, const int* in_sizes, int n_in,
                              void* d_out, int out_size, void* d_ws, size_t ws_size,
                              hipStream_t stream)
{
    const float4* inp  = (const float4*)d_in[0];
    const float*  aabb = (const float*)d_in[1];
    PlanePtrs ptrs;
    for (int i = 0; i < 9; ++i) ptrs.p[i] = (const float*)d_in[2 + i];
    const float* w0 = (const float*)d_in[11];
    const float* b0 = (const float*)d_in[12];
    const float* w1 = (const float*)d_in[13];
    const float* b1 = (const float*)d_in[14];
    float* out = (float*)d_out;
    const int N = in_sizes[0] / 4;

    if (ws_size >= WS_NEED) {
        __half* planes = (__half*)d_ws;
        k_transpose<<<TOTAL_TEXELS / 256, 256, 0, stream>>>(ptrs, planes);
        int nb = N / 64;
        if (nb > 0)
            k_main<<<nb, 64, 0, stream>>>(inp, aabb, planes, w0, b0, w1, b1, out);
        int done = nb * 64;
        int rem = N - done;
        if (rem > 0)
            k_fallback<<<(rem + 255) / 256, 256, 0, stream>>>(inp, aabb, ptrs, w0, b0, w1, b1, out, N, done);
    } else {
        k_fallback<<<(N + 255) / 256, 256, 0, stream>>>(inp, aabb, ptrs, w0, b0, w1, b1, out, N, 0);
    }
}